// Round 1
// baseline (662.125 us; speedup 1.0000x reference)
//
#include <hip/hip_runtime.h>
#include <stdint.h>

typedef unsigned short ushort_t;
typedef __attribute__((ext_vector_type(4))) float f32x4;
typedef __attribute__((ext_vector_type(8))) short bf16x8;

#define TM 128
#define TN 128
#define BK 64

// ---------- helpers ----------

// round-to-nearest-even float -> bf16 (for weight dequant; values inexact)
__device__ __forceinline__ ushort_t f2bf_rne(float f) {
  union { float f; uint32_t u; } v; v.f = f;
  return (ushort_t)((v.u + 0x7FFFu + ((v.u >> 16) & 1u)) >> 16);
}

// truncating float -> bf16; EXACT for integers in [-256,256]
__device__ __forceinline__ ushort_t f2bf_exact(float f) {
  union { float f; uint32_t u; } v; v.f = f;
  return (ushort_t)(v.u >> 16);
}

// async global -> LDS, 16 bytes per lane. LDS dest = wave-uniform base + lane*16.
__device__ __forceinline__ void async16(const void* g, void* l) {
  __builtin_amdgcn_global_load_lds(
      (__attribute__((address_space(1))) void*)g,
      (__attribute__((address_space(3))) void*)l,
      16, 0, 0);
}

// ---------- kernel 1: per-token dynamic quant, store (q - zp) as exact bf16 ----------
// one 256-thread block per token; K must be 4096 (256*16)
__global__ __launch_bounds__(256) void quant_kernel(
    const float* __restrict__ x, ushort_t* __restrict__ Aq,
    float* __restrict__ tokScale, int K)
{
  const int token = blockIdx.x;
  const int t = threadIdx.x;
  const float* xr = x + (size_t)token * K + t * 16;

  float xv[16];
  {
    const float4* p = (const float4*)xr;
    float4 a = p[0], b = p[1], c = p[2], d = p[3];
    xv[0]=a.x; xv[1]=a.y; xv[2]=a.z; xv[3]=a.w;
    xv[4]=b.x; xv[5]=b.y; xv[6]=b.z; xv[7]=b.w;
    xv[8]=c.x; xv[9]=c.y; xv[10]=c.z; xv[11]=c.w;
    xv[12]=d.x; xv[13]=d.y; xv[14]=d.z; xv[15]=d.w;
  }

  float mn = xv[0], mx = xv[0];
#pragma unroll
  for (int i = 1; i < 16; ++i) { mn = fminf(mn, xv[i]); mx = fmaxf(mx, xv[i]); }
#pragma unroll
  for (int off = 32; off >= 1; off >>= 1) {
    mn = fminf(mn, __shfl_xor(mn, off));
    mx = fmaxf(mx, __shfl_xor(mx, off));
  }

  __shared__ float smn[4], smx[4];
  const int wave = t >> 6, lane = t & 63;
  if (lane == 0) { smn[wave] = mn; smx[wave] = mx; }
  __syncthreads();
  mn = fminf(fminf(smn[0], smn[1]), fminf(smn[2], smn[3]));
  mx = fmaxf(fmaxf(smx[0], smx[1]), fmaxf(smx[2], smx[3]));

  mn = fminf(mn, 0.0f);
  mx = fmaxf(mx, 0.0f);
  const float scale = fmaxf((mx - mn) / 255.0f, 1.1920929e-07f);
  float zp = -128.0f - rintf(mn / scale);        // QMIN_A - round(mn/scale)
  zp = fminf(fmaxf(zp, -128.0f), 127.0f);

  ushort_t qb[16];
#pragma unroll
  for (int i = 0; i < 16; ++i) {
    float q = rintf(xv[i] / scale) + zp;         // round half-to-even, like jnp.round
    q = fminf(fmaxf(q, -128.0f), 127.0f);
    qb[i] = f2bf_exact(q - zp);                  // integer in [-255,255]: exact in bf16
  }

  uint32_t w[8];
#pragma unroll
  for (int i = 0; i < 8; ++i)
    w[i] = (uint32_t)qb[2*i] | ((uint32_t)qb[2*i+1] << 16);

  ushort_t* dst = Aq + (size_t)token * K + t * 16;
  uint4 o0 = make_uint4(w[0], w[1], w[2], w[3]);
  uint4 o1 = make_uint4(w[4], w[5], w[6], w[7]);
  ((uint4*)dst)[0] = o0;
  ((uint4*)dst)[1] = o1;

  if (t == 0) tokScale[token] = scale;
}

// ---------- kernel 2: groupwise int4 weight dequant -> bf16 ----------
// one block per output row; thread t handles 16 cols at t*16 (K must be 4096)
__global__ __launch_bounds__(256) void wdq_kernel(
    const int* __restrict__ W, const float* __restrict__ scales,
    const float* __restrict__ zeros, ushort_t* __restrict__ Wq,
    int K, int gpr, int G)
{
  const int row = blockIdx.x;
  const int t = threadIdx.x;
  const int col = t * 16;
  const int g = col / G;
  const float s = scales[(size_t)row * gpr + g];
  const float zq = zeros[(size_t)row * gpr + g];

  const int4* wp = (const int4*)(W + (size_t)row * K + col);
  ushort_t qb[16];
#pragma unroll
  for (int v = 0; v < 4; ++v) {
    int4 w4 = wp[v];
    qb[v*4+0] = f2bf_rne(((float)w4.x - zq) * s);
    qb[v*4+1] = f2bf_rne(((float)w4.y - zq) * s);
    qb[v*4+2] = f2bf_rne(((float)w4.z - zq) * s);
    qb[v*4+3] = f2bf_rne(((float)w4.w - zq) * s);
  }

  uint32_t w[8];
#pragma unroll
  for (int i = 0; i < 8; ++i)
    w[i] = (uint32_t)qb[2*i] | ((uint32_t)qb[2*i+1] << 16);

  ushort_t* dst = Wq + (size_t)row * K + col;
  ((uint4*)dst)[0] = make_uint4(w[0], w[1], w[2], w[3]);
  ((uint4*)dst)[1] = make_uint4(w[4], w[5], w[6], w[7]);
}

// ---------- kernel 3: bf16 MFMA GEMM (m97 structure), fused scale_tok + bias ----------
// C[m,n] = tokScale[m] * sum_k A[m,k]*B[n,k] + bias[n]
__global__ __launch_bounds__(256) void gemm_kernel(
    const ushort_t* __restrict__ A,   // M x K bf16 (q - zp), exact integers
    const ushort_t* __restrict__ B,   // N x K bf16 dequant weights
    const float* __restrict__ tokScale,
    const float* __restrict__ bias,
    float* __restrict__ C, int M, int N, int K)
{
  __shared__ __align__(16) ushort_t As[TM * BK];
  __shared__ __align__(16) ushort_t Bs[TN * BK];

  const int tid  = threadIdx.x;
  const int lane = tid & 63;
  const int wave = tid >> 6;
  const int m0 = blockIdx.y * TM;
  const int n0 = blockIdx.x * TN;
  const int wm = (wave & 1) * 64;
  const int wn = (wave >> 1) * 64;
  const int row16 = lane & 15;
  const int quad  = lane >> 4;

  f32x4 acc[4][4];
#pragma unroll
  for (int i = 0; i < 4; ++i)
#pragma unroll
    for (int j = 0; j < 4; ++j)
      acc[i][j] = (f32x4){0.f, 0.f, 0.f, 0.f};

  for (int k0 = 0; k0 < K; k0 += BK) {
    // stage A and B tiles: 1024 16-B chunks each, 4 per thread per tile.
    // chunk -> LDS element offset chunk*8 == row*BK + col (row=chunk>>3, col=(chunk&7)*8)
    // wave-uniform LDS base + lane*16B matches this order exactly (no padding).
#pragma unroll
    for (int it = 0; it < 4; ++it) {
      const int chunk = (it << 8) + tid;
      const int r = chunk >> 3;
      const int c = (chunk & 7) << 3;
      const int ldsbase = it * 2048 + wave * 512;   // elements
      async16(A + (size_t)(m0 + r) * K + (k0 + c), &As[ldsbase]);
      async16(B + (size_t)(n0 + r) * K + (k0 + c), &Bs[ldsbase]);
    }
    __syncthreads();   // drains vmcnt (global_load_lds) + barrier

#pragma unroll
    for (int kk = 0; kk < BK; kk += 32) {
      bf16x8 af[4], bv[4];
#pragma unroll
      for (int i = 0; i < 4; ++i)
        af[i] = *(const bf16x8*)&As[(wm + i * 16 + row16) * BK + kk + quad * 8];
#pragma unroll
      for (int j = 0; j < 4; ++j)
        bv[j] = *(const bf16x8*)&Bs[(wn + j * 16 + row16) * BK + kk + quad * 8];
#pragma unroll
      for (int i = 0; i < 4; ++i)
#pragma unroll
        for (int j = 0; j < 4; ++j)
          acc[i][j] = __builtin_amdgcn_mfma_f32_16x16x32_bf16(af[i], bv[j], acc[i][j], 0, 0, 0);
    }
    __syncthreads();
  }

  // epilogue: C/D layout col=lane&15, row=quad*4+reg (verified m89/m91)
#pragma unroll
  for (int i = 0; i < 4; ++i) {
    const int mb = m0 + wm + i * 16 + quad * 4;
#pragma unroll
    for (int r = 0; r < 4; ++r) {
      const float ts = tokScale[mb + r];
      float* crow = C + (size_t)(mb + r) * N;
#pragma unroll
      for (int j = 0; j < 4; ++j) {
        const int n = n0 + wn + j * 16 + row16;
        crow[n] = acc[i][j][r] * ts + bias[n];
      }
    }
  }
}

// ---------- launch ----------
extern "C" void kernel_launch(void* const* d_in, const int* in_sizes, int n_in,
                              void* d_out, int out_size, void* d_ws, size_t ws_size,
                              hipStream_t stream) {
  const float* x      = (const float*)d_in[0];
  const int*   w      = (const int*)d_in[1];    // int inputs arrive as int32
  const float* scales = (const float*)d_in[2];
  const float* zeros  = (const float*)d_in[3];
  const float* bias   = (const float*)d_in[4];
  float* out = (float*)d_out;

  const int OUT = in_sizes[4];                  // 4096
  const int IN  = in_sizes[1] / OUT;            // 4096
  const int M   = in_sizes[0] / IN;             // 8192 tokens
  const int gpr = in_sizes[2] / OUT;            // 16 groups per row
  const int G   = IN / gpr;                     // 256

  // workspace layout: A bf16 (M*IN), Wdq bf16 (OUT*IN), tokScale f32 (M)
  ushort_t* Aq = (ushort_t*)d_ws;
  ushort_t* Wq = Aq + (size_t)M * IN;
  float* tokScale = (float*)(Wq + (size_t)OUT * IN);

  quant_kernel<<<M, 256, 0, stream>>>(x, Aq, tokScale, IN);
  wdq_kernel<<<OUT, 256, 0, stream>>>(w, scales, zeros, Wq, IN, gpr, G);
  gemm_kernel<<<dim3(OUT / TN, M / TM), 256, 0, stream>>>(
      Aq, Wq, tokScale, bias, out, M, OUT, IN);
}

// Round 2
// 598.907 us; speedup vs baseline: 1.1056x; 1.1056x over previous
//
#include <hip/hip_runtime.h>
#include <stdint.h>

typedef unsigned short ushort_t;
typedef __attribute__((ext_vector_type(4))) float f32x4;
typedef __attribute__((ext_vector_type(8))) short bf16x8;

#define TM 128
#define TN 128
#define BK 64

// ---------- helpers ----------

// round-to-nearest-even float -> bf16 (for weight dequant; values inexact)
__device__ __forceinline__ ushort_t f2bf_rne(float f) {
  union { float f; uint32_t u; } v; v.f = f;
  return (ushort_t)((v.u + 0x7FFFu + ((v.u >> 16) & 1u)) >> 16);
}

// truncating float -> bf16; EXACT for integers in [-256,256]
__device__ __forceinline__ ushort_t f2bf_exact(float f) {
  union { float f; uint32_t u; } v; v.f = f;
  return (ushort_t)(v.u >> 16);
}

// async global -> LDS, 16 bytes per lane. LDS dest = wave-uniform base + lane*16.
__device__ __forceinline__ void async16(const void* g, void* l) {
  __builtin_amdgcn_global_load_lds(
      (__attribute__((address_space(1))) void*)g,
      (__attribute__((address_space(3))) void*)l,
      16, 0, 0);
}

// ---------- kernel 1: per-token dynamic quant, store (q - zp) as exact bf16 ----------
// one 256-thread block per token; thread t handles float4 chunks t+256*j (coalesced)
__global__ __launch_bounds__(256) void quant_kernel(
    const float* __restrict__ x, ushort_t* __restrict__ Aq,
    float* __restrict__ tokScale, int K)
{
  const int token = blockIdx.x;
  const int t = threadIdx.x;
  const float4* xin = (const float4*)(x + (size_t)token * K);

  float4 v[4];
#pragma unroll
  for (int j = 0; j < 4; ++j) v[j] = xin[t + 256 * j];   // 16B/lane, contiguous across lanes

  float mn = v[0].x, mx = v[0].x;
#pragma unroll
  for (int j = 0; j < 4; ++j) {
    mn = fminf(mn, fminf(fminf(v[j].x, v[j].y), fminf(v[j].z, v[j].w)));
    mx = fmaxf(mx, fmaxf(fmaxf(v[j].x, v[j].y), fmaxf(v[j].z, v[j].w)));
  }
#pragma unroll
  for (int off = 32; off >= 1; off >>= 1) {
    mn = fminf(mn, __shfl_xor(mn, off));
    mx = fmaxf(mx, __shfl_xor(mx, off));
  }

  __shared__ float smn[4], smx[4];
  const int wave = t >> 6, lane = t & 63;
  if (lane == 0) { smn[wave] = mn; smx[wave] = mx; }
  __syncthreads();
  mn = fminf(fminf(smn[0], smn[1]), fminf(smn[2], smn[3]));
  mx = fmaxf(fmaxf(smx[0], smx[1]), fmaxf(smx[2], smx[3]));

  mn = fminf(mn, 0.0f);
  mx = fmaxf(mx, 0.0f);
  const float scale = fmaxf((mx - mn) / 255.0f, 1.1920929e-07f);
  float zp = -128.0f - rintf(mn / scale);        // one exact division
  zp = fminf(fmaxf(zp, -128.0f), 127.0f);
  const float rs = 1.0f / scale;                 // one exact division; then multiplies

  ushort_t* dst = Aq + (size_t)token * K;
#pragma unroll
  for (int j = 0; j < 4; ++j) {
    float e[4] = {v[j].x, v[j].y, v[j].z, v[j].w};
    ushort_t qb[4];
#pragma unroll
    for (int i = 0; i < 4; ++i) {
      float q = rintf(e[i] * rs) + zp;           // half-to-even, like jnp.round
      q = fminf(fmaxf(q, -128.0f), 127.0f);
      qb[i] = f2bf_exact(q - zp);                // integer in [-255,255]: exact in bf16
    }
    uint2 o;
    o.x = (uint32_t)qb[0] | ((uint32_t)qb[1] << 16);
    o.y = (uint32_t)qb[2] | ((uint32_t)qb[3] << 16);
    ((uint2*)dst)[t + 256 * j] = o;              // 8B/lane, contiguous across lanes
  }

  if (t == 0) tokScale[token] = scale;
}

// ---------- kernel 2: groupwise int4 weight dequant -> bf16 ----------
// one block per output row; thread t handles int4 chunks t+256*j (coalesced)
__global__ __launch_bounds__(256) void wdq_kernel(
    const int* __restrict__ W, const float* __restrict__ scales,
    const float* __restrict__ zeros, ushort_t* __restrict__ Wq,
    int K, int gpr, int G)
{
  const int row = blockIdx.x;
  const int t = threadIdx.x;
  const size_t rb = (size_t)row * K;
  const int4* wp = (const int4*)(W + rb);
  ushort_t* dst = Wq + rb;

#pragma unroll
  for (int j = 0; j < 4; ++j) {
    const int idx = t + 256 * j;          // int4-chunk index; col = idx*4
    const int g = (idx * 4) / G;
    const float s = scales[(size_t)row * gpr + g];
    const float zq = zeros[(size_t)row * gpr + g];
    int4 w4 = wp[idx];
    uint2 o;
    o.x = (uint32_t)f2bf_rne(((float)w4.x - zq) * s)
        | ((uint32_t)f2bf_rne(((float)w4.y - zq) * s) << 16);
    o.y = (uint32_t)f2bf_rne(((float)w4.z - zq) * s)
        | ((uint32_t)f2bf_rne(((float)w4.w - zq) * s) << 16);
    ((uint2*)dst)[idx] = o;
  }
}

// ---------- kernel 3: bf16 MFMA GEMM (m97 structure + XOR-swizzled LDS) ----------
// C[m,n] = tokScale[m] * sum_k A[m,k]*B[n,k] + bias[n]
//
// LDS swizzle: chunk position p=(r, c') in LDS holds global chunk (r, c'^(r&7)).
// Staging keeps the wave-uniform-base + lane*16 dest order (global_load_lds
// constraint); the permutation is applied on the GLOBAL side. Fragment reads
// use col_chunk = ((kk/8+quad) ^ (row&7)) so each aligned 8-lane phase of a
// ds_read_b128 covers all 8 chunk-columns = all 32 banks -> conflict-free.
__global__ __launch_bounds__(256) void gemm_kernel(
    const ushort_t* __restrict__ A,   // M x K bf16 (q - zp), exact integers
    const ushort_t* __restrict__ B,   // N x K bf16 dequant weights
    const float* __restrict__ tokScale,
    const float* __restrict__ bias,
    float* __restrict__ C, int M, int N, int K)
{
  __shared__ __align__(16) ushort_t As[TM * BK];
  __shared__ __align__(16) ushort_t Bs[TN * BK];

  const int tid  = threadIdx.x;
  const int lane = tid & 63;
  const int wave = tid >> 6;
  const int m0 = blockIdx.y * TM;
  const int n0 = blockIdx.x * TN;
  const int wm = (wave & 1) * 64;
  const int wn = (wave >> 1) * 64;
  const int row16 = lane & 15;
  const int quad  = lane >> 4;
  const int sw    = row16 & 7;        // row-dependent XOR key (wm, i*16 are mult of 8)

  f32x4 acc[4][4];
#pragma unroll
  for (int i = 0; i < 4; ++i)
#pragma unroll
    for (int j = 0; j < 4; ++j)
      acc[i][j] = (f32x4){0.f, 0.f, 0.f, 0.f};

  for (int k0 = 0; k0 < K; k0 += BK) {
#pragma unroll
    for (int it = 0; it < 4; ++it) {
      const int p = (it << 8) + tid;           // LDS chunk position
      const int r = p >> 3;                    // tile row
      const int c = (p & 7) ^ (r & 7);         // swizzled global chunk col
      const int ldsoff = it * 2048 + wave * 512;  // wave-uniform base (elements)
      async16(A + (size_t)(m0 + r) * K + k0 + (c << 3), &As[ldsoff]);
      async16(B + (size_t)(n0 + r) * K + k0 + (c << 3), &Bs[ldsoff]);
    }
    __syncthreads();   // drains vmcnt (global_load_lds) + barrier

#pragma unroll
    for (int kk = 0; kk < BK; kk += 32) {
      const int kb = kk >> 3;                  // base chunk col
      bf16x8 af[4], bv[4];
#pragma unroll
      for (int i = 0; i < 4; ++i)
        af[i] = *(const bf16x8*)&As[(wm + i * 16 + row16) * BK + ((((kb + quad) ^ sw)) << 3)];
#pragma unroll
      for (int j = 0; j < 4; ++j)
        bv[j] = *(const bf16x8*)&Bs[(wn + j * 16 + row16) * BK + ((((kb + quad) ^ sw)) << 3)];
#pragma unroll
      for (int i = 0; i < 4; ++i)
#pragma unroll
        for (int j = 0; j < 4; ++j)
          acc[i][j] = __builtin_amdgcn_mfma_f32_16x16x32_bf16(af[i], bv[j], acc[i][j], 0, 0, 0);
    }
    __syncthreads();
  }

  // epilogue: C/D layout col=lane&15, row=quad*4+reg (verified m89/m91)
#pragma unroll
  for (int i = 0; i < 4; ++i) {
    const int mb = m0 + wm + i * 16 + quad * 4;
#pragma unroll
    for (int r = 0; r < 4; ++r) {
      const float ts = tokScale[mb + r];
      float* crow = C + (size_t)(mb + r) * N;
#pragma unroll
      for (int j = 0; j < 4; ++j) {
        const int n = n0 + wn + j * 16 + row16;
        crow[n] = acc[i][j][r] * ts + bias[n];
      }
    }
  }
}

// ---------- launch ----------
extern "C" void kernel_launch(void* const* d_in, const int* in_sizes, int n_in,
                              void* d_out, int out_size, void* d_ws, size_t ws_size,
                              hipStream_t stream) {
  const float* x      = (const float*)d_in[0];
  const int*   w      = (const int*)d_in[1];    // int inputs arrive as int32
  const float* scales = (const float*)d_in[2];
  const float* zeros  = (const float*)d_in[3];
  const float* bias   = (const float*)d_in[4];
  float* out = (float*)d_out;

  const int OUT = in_sizes[4];                  // 4096
  const int IN  = in_sizes[1] / OUT;            // 4096
  const int M   = in_sizes[0] / IN;             // 8192 tokens
  const int gpr = in_sizes[2] / OUT;            // 16 groups per row
  const int G   = IN / gpr;                     // 256

  // workspace layout: A bf16 (M*IN), Wdq bf16 (OUT*IN), tokScale f32 (M)
  ushort_t* Aq = (ushort_t*)d_ws;
  ushort_t* Wq = Aq + (size_t)M * IN;
  float* tokScale = (float*)(Wq + (size_t)OUT * IN);

  quant_kernel<<<M, 256, 0, stream>>>(x, Aq, tokScale, IN);
  wdq_kernel<<<OUT, 256, 0, stream>>>(w, scales, zeros, Wq, IN, gpr, G);
  gemm_kernel<<<dim3(OUT / TN, M / TM), 256, 0, stream>>>(
      Aq, Wq, tokScale, bias, out, M, OUT, IN);
}

// Round 3
// 449.484 us; speedup vs baseline: 1.4731x; 1.3324x over previous
//
#include <hip/hip_runtime.h>
#include <stdint.h>

typedef unsigned short ushort_t;
typedef __attribute__((ext_vector_type(4))) int   i32x4;
typedef __attribute__((ext_vector_type(16))) int  i32x16;

#define TM 128
#define TN 128
#define BKB 128   // K-slice per stage, BYTES (int8 elems); group = 256 = 2*BKB

// ---------- helpers ----------

// async global -> LDS, 16 bytes per lane. LDS dest = wave-uniform base + lane*16.
__device__ __forceinline__ void async16(const void* g, void* l) {
  __builtin_amdgcn_global_load_lds(
      (__attribute__((address_space(1))) void*)g,
      (__attribute__((address_space(3))) void*)l,
      16, 0, 0);
}

// ---------- kernel 1: per-token dynamic quant -> int8 q, plus scale & zp ----------
// one 256-thread block per token; thread t handles float4 chunks t+256*j (coalesced)
__global__ __launch_bounds__(256) void quant_kernel(
    const float* __restrict__ x, int8_t* __restrict__ Aq,
    float* __restrict__ tokScale, float* __restrict__ tokZp, int K)
{
  const int token = blockIdx.x;
  const int t = threadIdx.x;
  const float4* xin = (const float4*)(x + (size_t)token * K);

  float4 v[4];
#pragma unroll
  for (int j = 0; j < 4; ++j) v[j] = xin[t + 256 * j];

  float mn = v[0].x, mx = v[0].x;
#pragma unroll
  for (int j = 0; j < 4; ++j) {
    mn = fminf(mn, fminf(fminf(v[j].x, v[j].y), fminf(v[j].z, v[j].w)));
    mx = fmaxf(mx, fmaxf(fmaxf(v[j].x, v[j].y), fmaxf(v[j].z, v[j].w)));
  }
#pragma unroll
  for (int off = 32; off >= 1; off >>= 1) {
    mn = fminf(mn, __shfl_xor(mn, off));
    mx = fmaxf(mx, __shfl_xor(mx, off));
  }

  __shared__ float smn[4], smx[4];
  const int wave = t >> 6, lane = t & 63;
  if (lane == 0) { smn[wave] = mn; smx[wave] = mx; }
  __syncthreads();
  mn = fminf(fminf(smn[0], smn[1]), fminf(smn[2], smn[3]));
  mx = fmaxf(fmaxf(smx[0], smx[1]), fmaxf(smx[2], smx[3]));

  mn = fminf(mn, 0.0f);
  mx = fmaxf(mx, 0.0f);
  const float scale = fmaxf((mx - mn) / 255.0f, 1.1920929e-07f);
  float zp = -128.0f - rintf(mn / scale);        // exact division, matches ref
  zp = fminf(fmaxf(zp, -128.0f), 127.0f);
  const float rs = 1.0f / scale;

  uint32_t* dst = (uint32_t*)(Aq + (size_t)token * K);
#pragma unroll
  for (int j = 0; j < 4; ++j) {
    float e[4] = {v[j].x, v[j].y, v[j].z, v[j].w};
    uint32_t pk = 0;
#pragma unroll
    for (int i = 0; i < 4; ++i) {
      float q = rintf(e[i] * rs) + zp;           // half-to-even, like jnp.round
      q = fminf(fmaxf(q, -128.0f), 127.0f);
      pk |= ((uint32_t)(int)q & 0xFFu) << (8 * i);
    }
    dst[t + 256 * j] = pk;                       // 4B/lane, contiguous across lanes
  }

  if (t == 0) { tokScale[token] = scale; tokZp[token] = zp; }
}

// ---------- kernel 2: weight prep: w' = w - zero (int8), T[n] = sum_k s*(w-z) ----------
// one block per output row; thread t handles int4 chunks t+256*j (coalesced)
__global__ __launch_bounds__(256) void wprep_kernel(
    const int* __restrict__ W, const float* __restrict__ scales,
    const float* __restrict__ zeros, int8_t* __restrict__ Wq,
    float* __restrict__ T, int K, int gpr, int G)
{
  const int row = blockIdx.x;
  const int t = threadIdx.x;
  const int4* wp = (const int4*)(W + (size_t)row * K);
  uint32_t* dst = (uint32_t*)(Wq + (size_t)row * K);

  float partial = 0.0f;
#pragma unroll
  for (int j = 0; j < 4; ++j) {
    const int idx = t + 256 * j;          // int4-chunk; cols idx*4..idx*4+3
    const int g = (idx * 4) / G;
    const float s = scales[(size_t)row * gpr + g];
    const int zi = (int)zeros[(size_t)row * gpr + g];   // integer-valued, exact
    int4 w4 = wp[idx];
    const int a = w4.x - zi, b = w4.y - zi, c = w4.z - zi, d = w4.w - zi;
    dst[idx] = ((uint32_t)a & 0xFFu) | (((uint32_t)b & 0xFFu) << 8)
             | (((uint32_t)c & 0xFFu) << 16) | (((uint32_t)d & 0xFFu) << 24);
    partial += s * (float)(a + b + c + d);
  }

  // block reduce -> T[row]
#pragma unroll
  for (int off = 32; off >= 1; off >>= 1) partial += __shfl_xor(partial, off);
  __shared__ float sp[4];
  const int wave = t >> 6, lane = t & 63;
  if (lane == 0) sp[wave] = partial;
  __syncthreads();
  if (t == 0) T[row] = (sp[0] + sp[1]) + (sp[2] + sp[3]);
}

// ---------- kernel 3: int8 MFMA GEMM with per-group fp32 fixup ----------
// out[m,n] = ts_m * ( sum_g s[n,g]*dot_g[m,n] - zp_m*T[n] ) + bias[n]
// dot_g = exact int32 sum over the 256-wide group of q[m,k]*w'[n,k].
//
// LDS XOR swizzle (verified R2, conflicts -> 0): chunk position (r,c') holds
// global 16-B chunk (r, c'^(r&7)); fragment reads XOR the wanted chunk col
// with (row&7). Same geometry as bf16 (8 chunks/row).
__global__ __launch_bounds__(256) void gemm_kernel(
    const int8_t* __restrict__ A,    // M x K int8 q
    const int8_t* __restrict__ B,    // N x K int8 w' = w - zero
    const float* __restrict__ scales,// N x gpr
    const float* __restrict__ tokScale, const float* __restrict__ tokZp,
    const float* __restrict__ T, const float* __restrict__ bias,
    float* __restrict__ C, int M, int N, int K, int gpr)
{
  __shared__ __align__(16) int8_t As[TM * BKB];
  __shared__ __align__(16) int8_t Bs[TN * BKB];
  __shared__ float sS[16 * TN];   // [g][n_local] scales, transposed for broadcast reads

  const int tid   = threadIdx.x;
  const int lane  = tid & 63;
  const int wave  = tid >> 6;
  const int m0 = blockIdx.y * TM;
  const int n0 = blockIdx.x * TN;
  const int wm = (wave & 1) * 64;
  const int wn = (wave >> 1) * 64;
  const int col32 = lane & 31;
  const int khalf = lane >> 5;          // picks which 16-B K-chunk of the frag

  // preload scales into LDS, transposed: coalesced global read
#pragma unroll
  for (int jj = 0; jj < (16 * TN) / 256; ++jj) {
    const int flat = tid + 256 * jj;
    const int i = flat >> 4, g = flat & 15;
    sS[g * TN + i] = scales[(size_t)(n0 + i) * gpr + g];
  }
  // (first __syncthreads in the k-loop orders these writes before any fixup read)

  float accf[2][2][16];
#pragma unroll
  for (int i = 0; i < 2; ++i)
#pragma unroll
    for (int j = 0; j < 2; ++j)
#pragma unroll
      for (int r = 0; r < 16; ++r) accf[i][j][r] = 0.0f;

  i32x16 zeroC;
#pragma unroll
  for (int r = 0; r < 16; ++r) zeroC[r] = 0;

  const int ngroups = K / 256;
  for (int g = 0; g < ngroups; ++g) {
    i32x16 ai[2][2];
#pragma unroll
    for (int half = 0; half < 2; ++half) {
      const int k0 = g * 256 + half * BKB;
      // stage A,B tiles: 1024 16-B chunks each, 4/thread
#pragma unroll
      for (int it = 0; it < 4; ++it) {
        const int p = (it << 8) + tid;
        const int r = p >> 3;
        const int c = (p & 7) ^ (r & 7);
        const int ldsoff = it * 4096 + wave * 1024;   // bytes, wave-uniform + lane*16
        async16(A + (size_t)(m0 + r) * K + k0 + (c << 4), &As[ldsoff]);
        async16(B + (size_t)(n0 + r) * K + k0 + (c << 4), &Bs[ldsoff]);
      }
      __syncthreads();

#pragma unroll
      for (int kk = 0; kk < 4; ++kk) {
        const int cw = kk * 2 + khalf;                // wanted 16-B chunk col
        i32x4 af[2], bf[2];
#pragma unroll
        for (int i = 0; i < 2; ++i) {
          const int r = wm + i * 32 + col32;
          af[i] = *(const i32x4*)&As[r * BKB + ((cw ^ (r & 7)) << 4)];
        }
#pragma unroll
        for (int j = 0; j < 2; ++j) {
          const int r = wn + j * 32 + col32;
          bf[j] = *(const i32x4*)&Bs[r * BKB + ((cw ^ (r & 7)) << 4)];
        }
#pragma unroll
        for (int i = 0; i < 2; ++i)
#pragma unroll
          for (int j = 0; j < 2; ++j) {
            if (half == 0 && kk == 0)
              ai[i][j] = __builtin_amdgcn_mfma_i32_32x32x32_i8(af[i], bf[j], zeroC, 0, 0, 0);
            else
              ai[i][j] = __builtin_amdgcn_mfma_i32_32x32x32_i8(af[i], bf[j], ai[i][j], 0, 0, 0);
          }
      }
      __syncthreads();
    }
    // per-group fixup: accf += s[n,g] * (float)dot_g
#pragma unroll
    for (int j = 0; j < 2; ++j) {
      const float s = sS[g * TN + wn + j * 32 + col32];
#pragma unroll
      for (int i = 0; i < 2; ++i)
#pragma unroll
        for (int r = 0; r < 16; ++r)
          accf[i][j][r] += s * (float)ai[i][j][r];
    }
  }

  // epilogue: C/D 32x32 layout col=lane&31, row=(reg&3)+8*(reg>>2)+4*(lane>>5)
  int   nj[2];
  float Tn[2], bn[2];
#pragma unroll
  for (int j = 0; j < 2; ++j) {
    nj[j] = n0 + wn + j * 32 + col32;
    Tn[j] = T[nj[j]];
    bn[j] = bias[nj[j]];
  }
  const int rbase = 4 * khalf;
#pragma unroll
  for (int i = 0; i < 2; ++i) {
    const int mb = m0 + wm + i * 32;
#pragma unroll
    for (int r = 0; r < 16; ++r) {
      const int m = mb + (r & 3) + 8 * (r >> 2) + rbase;
      const float ts = tokScale[m];
      const float zp = tokZp[m];
      float* crow = C + (size_t)m * N;
#pragma unroll
      for (int j = 0; j < 2; ++j)
        crow[nj[j]] = ts * (accf[i][j][r] - zp * Tn[j]) + bn[j];
    }
  }
}

// ---------- launch ----------
extern "C" void kernel_launch(void* const* d_in, const int* in_sizes, int n_in,
                              void* d_out, int out_size, void* d_ws, size_t ws_size,
                              hipStream_t stream) {
  const float* x      = (const float*)d_in[0];
  const int*   w      = (const int*)d_in[1];    // int inputs arrive as int32
  const float* scales = (const float*)d_in[2];
  const float* zeros  = (const float*)d_in[3];
  const float* bias   = (const float*)d_in[4];
  float* out = (float*)d_out;

  const int OUT = in_sizes[4];                  // 4096
  const int IN  = in_sizes[1] / OUT;            // 4096
  const int M   = in_sizes[0] / IN;             // 8192 tokens
  const int gpr = in_sizes[2] / OUT;            // 16 groups per row
  const int G   = IN / gpr;                     // 256

  // workspace: Aq int8 (M*IN), Wq int8 (OUT*IN), tokScale f32 (M), tokZp f32 (M), T f32 (OUT)
  int8_t* Aq = (int8_t*)d_ws;
  int8_t* Wq = Aq + (size_t)M * IN;
  float* tokScale = (float*)(Wq + (size_t)OUT * IN);
  float* tokZp = tokScale + M;
  float* T = tokZp + M;

  quant_kernel<<<M, 256, 0, stream>>>(x, Aq, tokScale, tokZp, IN);
  wprep_kernel<<<OUT, 256, 0, stream>>>(w, scales, zeros, Wq, T, IN, gpr, G);
  gemm_kernel<<<dim3(OUT / TN, M / TM), 256, 0, stream>>>(
      Aq, Wq, scales, tokScale, tokZp, T, bias, out, M, OUT, IN, gpr);
}

// Round 4
// 441.259 us; speedup vs baseline: 1.5005x; 1.0186x over previous
//
#include <hip/hip_runtime.h>
#include <stdint.h>

typedef unsigned short ushort_t;
typedef __attribute__((ext_vector_type(4))) int   i32x4;
typedef __attribute__((ext_vector_type(16))) int  i32x16;

#define TM 128
#define TN 128
#define BKB 128   // K-slice per stage, BYTES (int8 elems); group = 256 = 2*BKB

// ---------- helpers ----------

// async global -> LDS, 16 bytes per lane. LDS dest = wave-uniform base + lane*16.
__device__ __forceinline__ void async16(const void* g, void* l) {
  __builtin_amdgcn_global_load_lds(
      (__attribute__((address_space(1))) void*)g,
      (__attribute__((address_space(3))) void*)l,
      16, 0, 0);
}

// swizzle key: rows 8 apart must map to different chunk columns (R3 post-mortem:
// key=(r&7) left stride-8 lane phases 4-way conflicted; adding r>>3 fixes it
// under both consecutive-8 and stride-8 ds phase groupings)
__device__ __forceinline__ int swz(int r) { return (r ^ (r >> 3)) & 7; }

// ---------- kernel 1: per-token dynamic quant -> int8 q, plus scale & zp ----------
// one 256-thread block per token; thread t handles float4 chunks t+256*j (coalesced)
__global__ __launch_bounds__(256) void quant_kernel(
    const float* __restrict__ x, int8_t* __restrict__ Aq,
    float* __restrict__ tokScale, float* __restrict__ tokZp, int K)
{
  const int token = blockIdx.x;
  const int t = threadIdx.x;
  const float4* xin = (const float4*)(x + (size_t)token * K);

  float4 v[4];
#pragma unroll
  for (int j = 0; j < 4; ++j) v[j] = xin[t + 256 * j];

  float mn = v[0].x, mx = v[0].x;
#pragma unroll
  for (int j = 0; j < 4; ++j) {
    mn = fminf(mn, fminf(fminf(v[j].x, v[j].y), fminf(v[j].z, v[j].w)));
    mx = fmaxf(mx, fmaxf(fmaxf(v[j].x, v[j].y), fmaxf(v[j].z, v[j].w)));
  }
#pragma unroll
  for (int off = 32; off >= 1; off >>= 1) {
    mn = fminf(mn, __shfl_xor(mn, off));
    mx = fmaxf(mx, __shfl_xor(mx, off));
  }

  __shared__ float smn[4], smx[4];
  const int wave = t >> 6, lane = t & 63;
  if (lane == 0) { smn[wave] = mn; smx[wave] = mx; }
  __syncthreads();
  mn = fminf(fminf(smn[0], smn[1]), fminf(smn[2], smn[3]));
  mx = fmaxf(fmaxf(smx[0], smx[1]), fmaxf(smx[2], smx[3]));

  mn = fminf(mn, 0.0f);
  mx = fmaxf(mx, 0.0f);
  const float scale = fmaxf((mx - mn) / 255.0f, 1.1920929e-07f);
  float zp = -128.0f - rintf(mn / scale);        // exact division, matches ref
  zp = fminf(fmaxf(zp, -128.0f), 127.0f);
  const float rs = 1.0f / scale;

  uint32_t* dst = (uint32_t*)(Aq + (size_t)token * K);
#pragma unroll
  for (int j = 0; j < 4; ++j) {
    float e[4] = {v[j].x, v[j].y, v[j].z, v[j].w};
    uint32_t pk = 0;
#pragma unroll
    for (int i = 0; i < 4; ++i) {
      float q = rintf(e[i] * rs) + zp;           // half-to-even, like jnp.round
      q = fminf(fmaxf(q, -128.0f), 127.0f);
      pk |= ((uint32_t)(int)q & 0xFFu) << (8 * i);
    }
    dst[t + 256 * j] = pk;                       // 4B/lane, contiguous across lanes
  }

  if (t == 0) { tokScale[token] = scale; tokZp[token] = zp; }
}

// ---------- kernel 2: weight prep: w' = w - zero (int8), T[n] = sum_k s*(w-z) ----------
// one block per output row; thread t handles int4 chunks t+256*j (coalesced)
__global__ __launch_bounds__(256) void wprep_kernel(
    const int* __restrict__ W, const float* __restrict__ scales,
    const float* __restrict__ zeros, int8_t* __restrict__ Wq,
    float* __restrict__ T, int K, int gpr, int G)
{
  const int row = blockIdx.x;
  const int t = threadIdx.x;
  const int4* wp = (const int4*)(W + (size_t)row * K);
  uint32_t* dst = (uint32_t*)(Wq + (size_t)row * K);

  float partial = 0.0f;
#pragma unroll
  for (int j = 0; j < 4; ++j) {
    const int idx = t + 256 * j;          // int4-chunk; cols idx*4..idx*4+3
    const int g = (idx * 4) / G;
    const float s = scales[(size_t)row * gpr + g];
    const int zi = (int)zeros[(size_t)row * gpr + g];   // integer-valued, exact
    int4 w4 = wp[idx];
    const int a = w4.x - zi, b = w4.y - zi, c = w4.z - zi, d = w4.w - zi;
    dst[idx] = ((uint32_t)a & 0xFFu) | (((uint32_t)b & 0xFFu) << 8)
             | (((uint32_t)c & 0xFFu) << 16) | (((uint32_t)d & 0xFFu) << 24);
    partial += s * (float)(a + b + c + d);
  }

  // block reduce -> T[row]
#pragma unroll
  for (int off = 32; off >= 1; off >>= 1) partial += __shfl_xor(partial, off);
  __shared__ float sp[4];
  const int wave = t >> 6, lane = t & 63;
  if (lane == 0) sp[wave] = partial;
  __syncthreads();
  if (t == 0) T[row] = (sp[0] + sp[1]) + (sp[2] + sp[3]);
}

// ---------- kernel 3: int8 MFMA GEMM with per-group fp32 fixup ----------
// out[m,n] = ts_m * ( sum_g s[n,g]*dot_g[m,n] - zp_m*T[n] ) + bias[n]
// dot_g = exact int32 sum over the 256-wide group of q[m,k]*w'[n,k].
//
// LDS swizzle: chunk position (r,c') holds global chunk (r, c'^swz(r)),
// swz(r)=(r^(r>>3))&7. Fragment reads XOR the wanted chunk col with swz(row).
__global__ __launch_bounds__(256) void gemm_kernel(
    const int8_t* __restrict__ A,    // M x K int8 q
    const int8_t* __restrict__ B,    // N x K int8 w' = w - zero
    const float* __restrict__ scales,// N x gpr
    const float* __restrict__ tokScale, const float* __restrict__ tokZp,
    const float* __restrict__ T, const float* __restrict__ bias,
    float* __restrict__ C, int M, int N, int K, int gpr)
{
  __shared__ __align__(16) int8_t As[TM * BKB];
  __shared__ __align__(16) int8_t Bs[TN * BKB];
  __shared__ float sS[16 * TN];   // [g][n_local] scales, transposed for broadcast reads

  const int tid   = threadIdx.x;
  const int lane  = tid & 63;
  const int wave  = tid >> 6;
  const int m0 = blockIdx.y * TM;
  const int n0 = blockIdx.x * TN;
  const int wm = (wave & 1) * 64;
  const int wn = (wave >> 1) * 64;
  const int col32 = lane & 31;
  const int khalf = lane >> 5;          // picks which 16-B K-chunk of the frag

  // per-fragment rows and swizzle keys (kk-invariant)
  int rA[2], kA[2], rB[2], kB[2];
#pragma unroll
  for (int i = 0; i < 2; ++i) {
    rA[i] = wm + i * 32 + col32;  kA[i] = (rA[i] ^ (rA[i] >> 3)) & 7;
    rB[i] = wn + i * 32 + col32;  kB[i] = (rB[i] ^ (rB[i] >> 3)) & 7;
  }

  // preload scales into LDS, transposed: coalesced global read
#pragma unroll
  for (int jj = 0; jj < (16 * TN) / 256; ++jj) {
    const int flat = tid + 256 * jj;
    const int i = flat >> 4, g = flat & 15;
    sS[g * TN + i] = scales[(size_t)(n0 + i) * gpr + g];
  }
  // (first __syncthreads in the k-loop orders these writes before any fixup read)

  float accf[2][2][16];
#pragma unroll
  for (int i = 0; i < 2; ++i)
#pragma unroll
    for (int j = 0; j < 2; ++j)
#pragma unroll
      for (int r = 0; r < 16; ++r) accf[i][j][r] = 0.0f;

  i32x16 zeroC;
#pragma unroll
  for (int r = 0; r < 16; ++r) zeroC[r] = 0;

  const int ngroups = K / 256;
  for (int g = 0; g < ngroups; ++g) {
    i32x16 ai[2][2];
#pragma unroll
    for (int half = 0; half < 2; ++half) {
      const int k0 = g * 256 + half * BKB;
      // stage A,B tiles: 1024 16-B chunks each, 4/thread
#pragma unroll
      for (int it = 0; it < 4; ++it) {
        const int p = (it << 8) + tid;
        const int r = p >> 3;
        const int c = (p & 7) ^ ((r ^ (r >> 3)) & 7);
        const int ldsoff = it * 4096 + wave * 1024;   // bytes, wave-uniform + lane*16
        async16(A + (size_t)(m0 + r) * K + k0 + (c << 4), &As[ldsoff]);
        async16(B + (size_t)(n0 + r) * K + k0 + (c << 4), &Bs[ldsoff]);
      }
      __syncthreads();

#pragma unroll
      for (int kk = 0; kk < 4; ++kk) {
        const int cw = kk * 2 + khalf;                // wanted 16-B chunk col
        i32x4 af[2], bf[2];
#pragma unroll
        for (int i = 0; i < 2; ++i)
          af[i] = *(const i32x4*)&As[rA[i] * BKB + ((cw ^ kA[i]) << 4)];
#pragma unroll
        for (int j = 0; j < 2; ++j)
          bf[j] = *(const i32x4*)&Bs[rB[j] * BKB + ((cw ^ kB[j]) << 4)];
#pragma unroll
        for (int i = 0; i < 2; ++i)
#pragma unroll
          for (int j = 0; j < 2; ++j) {
            if (half == 0 && kk == 0)
              ai[i][j] = __builtin_amdgcn_mfma_i32_32x32x32_i8(af[i], bf[j], zeroC, 0, 0, 0);
            else
              ai[i][j] = __builtin_amdgcn_mfma_i32_32x32x32_i8(af[i], bf[j], ai[i][j], 0, 0, 0);
          }
      }
      __syncthreads();
    }
    // per-group fixup: accf += s[n,g] * (float)dot_g
#pragma unroll
    for (int j = 0; j < 2; ++j) {
      const float s = sS[g * TN + wn + j * 32 + col32];
#pragma unroll
      for (int i = 0; i < 2; ++i)
#pragma unroll
        for (int r = 0; r < 16; ++r)
          accf[i][j][r] += s * (float)ai[i][j][r];
    }
  }

  // epilogue: C/D 32x32 layout col=lane&31, row=(reg&3)+8*(reg>>2)+4*(lane>>5)
  int   nj[2];
  float Tn[2], bn[2];
#pragma unroll
  for (int j = 0; j < 2; ++j) {
    nj[j] = n0 + wn + j * 32 + col32;
    Tn[j] = T[nj[j]];
    bn[j] = bias[nj[j]];
  }
  const int rbase = 4 * khalf;
#pragma unroll
  for (int i = 0; i < 2; ++i) {
    const int mb = m0 + wm + i * 32;
#pragma unroll
    for (int r = 0; r < 16; ++r) {
      const int m = mb + (r & 3) + 8 * (r >> 2) + rbase;
      const float ts = tokScale[m];
      const float zp = tokZp[m];
      float* crow = C + (size_t)m * N;
#pragma unroll
      for (int j = 0; j < 2; ++j)
        crow[nj[j]] = ts * (accf[i][j][r] - zp * Tn[j]) + bn[j];
    }
  }
}

// ---------- launch ----------
extern "C" void kernel_launch(void* const* d_in, const int* in_sizes, int n_in,
                              void* d_out, int out_size, void* d_ws, size_t ws_size,
                              hipStream_t stream) {
  const float* x      = (const float*)d_in[0];
  const int*   w      = (const int*)d_in[1];    // int inputs arrive as int32
  const float* scales = (const float*)d_in[2];
  const float* zeros  = (const float*)d_in[3];
  const float* bias   = (const float*)d_in[4];
  float* out = (float*)d_out;

  const int OUT = in_sizes[4];                  // 4096
  const int IN  = in_sizes[1] / OUT;            // 4096
  const int M   = in_sizes[0] / IN;             // 8192 tokens
  const int gpr = in_sizes[2] / OUT;            // 16 groups per row
  const int G   = IN / gpr;                     // 256

  // workspace: Aq int8 (M*IN), Wq int8 (OUT*IN), tokScale f32 (M), tokZp f32 (M), T f32 (OUT)
  int8_t* Aq = (int8_t*)d_ws;
  int8_t* Wq = Aq + (size_t)M * IN;
  float* tokScale = (float*)(Wq + (size_t)OUT * IN);
  float* tokZp = tokScale + M;
  float* T = tokZp + M;

  quant_kernel<<<M, 256, 0, stream>>>(x, Aq, tokScale, tokZp, IN);
  wprep_kernel<<<OUT, 256, 0, stream>>>(w, scales, zeros, Wq, T, IN, gpr, G);
  gemm_kernel<<<dim3(OUT / TN, M / TM), 256, 0, stream>>>(
      Aq, Wq, scales, tokScale, tokZp, T, bias, out, M, OUT, IN, gpr);
}